// Round 1
// baseline (193.712 us; speedup 1.0000x reference)
//
#include <hip/hip_runtime.h>

#define BSZ   2
#define LSEQ  2048
#define DQ    512
#define SQ    4
#define CHUNK 32
#define NCH   (LSEQ / CHUNK)   // 64 chunks == wave size for pass2 scan
#define EPSQ  1e-6f

struct Quat { float r, i, j, k; };

__device__ __forceinline__ Quat qmul(const Quat a, const Quat b) {
    Quat o;
    o.r = a.r*b.r - a.i*b.i - a.j*b.j - a.k*b.k;
    o.i = a.r*b.i + a.i*b.r + a.j*b.k - a.k*b.j;
    o.j = a.r*b.j - a.i*b.k + a.j*b.r + a.k*b.i;
    o.k = a.r*b.k + a.i*b.j - a.j*b.i + a.k*b.r;
    return o;
}

// a*b + c
__device__ __forceinline__ Quat qmuladd(const Quat a, const Quat b, const Quat c) {
    Quat o;
    o.r = c.r + a.r*b.r - a.i*b.i - a.j*b.j - a.k*b.k;
    o.i = c.i + a.r*b.i + a.i*b.r + a.j*b.k - a.k*b.j;
    o.j = c.j + a.r*b.j - a.i*b.k + a.j*b.r + a.k*b.i;
    o.k = c.k + a.r*b.k + a.i*b.j - a.j*b.i + a.k*b.r;
    return o;
}

// Given dt scalar a, hA = 0.5*A_quat (A.r = -exp(A_log)), B quat, u quat:
// produce Cayley transition q and input injection Bu.
// q   = s*(1-|w|^2, 2wi, 2wj, 2wk),  w = a*hA, s = 1/((1-wr)^2+|w_im|^2+eps)
// dB  = (a*s) * (conj(den) x B),  conj(den) = (1-wr, wi, wj, wk)
// Bu  = dB x u
__device__ __forceinline__ void cayley_step(const float a, const float4 hA,
                                            const float4 Bq, const float4 uq,
                                            Quat& q, Quat& Bu) {
    const float wr = a * hA.x;
    const float wi = a * hA.y;
    const float wj = a * hA.z;
    const float wk = a * hA.w;
    const float m  = wi*wi + wj*wj + wk*wk;
    const float e  = 1.0f - wr;
    const float dd = e*e + m + EPSQ;
    const float sv = __builtin_amdgcn_rcpf(dd);
    const float s2 = sv + sv;
    q.r = sv * (1.0f - (wr*wr + m));
    q.i = s2 * wi; q.j = s2 * wj; q.k = s2 * wk;
    const Quat cd{e, wi, wj, wk};
    const Quat B { Bq.x, Bq.y, Bq.z, Bq.w };
    const Quat cb = qmul(cd, B);
    const float as = a * sv;
    const Quat dB{as*cb.r, as*cb.i, as*cb.j, as*cb.k};
    const Quat U { uq.x, uq.y, uq.z, uq.w };
    Bu = qmul(dB, U);
}

__device__ __forceinline__ float4 load_hA(const float* __restrict__ Alog,
                                          const float* __restrict__ Ai,
                                          const float* __restrict__ Aj,
                                          const float* __restrict__ Ak, int idx) {
    float4 hA;
    hA.x = -0.5f * expf(Alog[idx]);
    hA.y =  0.5f * Ai[idx];
    hA.z =  0.5f * Aj[idx];
    hA.w =  0.5f * Ak[idx];
    return hA;
}

// ---------------- pass 1: per (b,d,s,chunk) chunk summaries (Q, B) -----------
// grid: (DQ/256, SQ*NCH, BSZ), block 256.  W layout: [b][s][c][d][8]
__global__ __launch_bounds__(256) void qssm_pass1(
    const float* __restrict__ u, const float* __restrict__ dt,
    const float* __restrict__ Bin,
    const float* __restrict__ Alog, const float* __restrict__ Ai,
    const float* __restrict__ Aj,   const float* __restrict__ Ak,
    float* __restrict__ W)
{
    const int d = blockIdx.x * 256 + threadIdx.x;
    const int s = blockIdx.y >> 6;       // NCH == 64
    const int c = blockIdx.y & (NCH - 1);
    const int b = blockIdx.z;

    const float4 hA = load_hA(Alog, Ai, Aj, Ak, d * SQ + s);

    const int t0 = c * CHUNK;
    const float*  dtp = dt + ((size_t)b * LSEQ + t0) * DQ + d;
    const float4* up  = (const float4*)u   + ((size_t)b * LSEQ + t0) * DQ + d;
    const float4* Bp  = (const float4*)Bin + ((size_t)b * LSEQ + t0) * SQ + s;

    Quat Q{1.f, 0.f, 0.f, 0.f};
    Quat Bacc{0.f, 0.f, 0.f, 0.f};

#pragma unroll 4
    for (int j = 0; j < CHUNK; ++j) {
        const float  a  = dtp[j * DQ];
        const float4 uq = up[j * DQ];
        const float4 Bq = Bp[j * SQ];
        Quat q, Bu;
        cayley_step(a, hA, Bq, uq, q, Bu);
        Bacc = qmuladd(q, Bacc, Bu);   // B' = q x B + Bu
        Q    = qmul(q, Q);             // Q' = q x Q
    }

    float* Wp = W + ((((size_t)b * SQ + s) * NCH + c) * DQ + d) * 8;
    *(float4*)(Wp)     = make_float4(Q.r, Q.i, Q.j, Q.k);
    *(float4*)(Wp + 4) = make_float4(Bacc.r, Bacc.i, Bacc.j, Bacc.k);
}

// ---------------- pass 2: per-channel wave scan over 64 chunks ---------------
// One wave per (b,d,s); lane == chunk. Overwrites B-slot of W with h_start.
__global__ __launch_bounds__(256) void qssm_pass2(float* __restrict__ W)
{
    const int wid  = blockIdx.x * 4 + (threadIdx.x >> 6);
    const int lane = threadIdx.x & 63;
    const int s = wid & 3;
    const int d = (wid >> 2) & (DQ - 1);
    const int b = wid >> 11;

    float* Wp = W + ((((size_t)b * SQ + s) * NCH + lane) * DQ + d) * 8;
    const float4 Qv = *(const float4*)(Wp);
    const float4 Bv = *(const float4*)(Wp + 4);
    Quat Q{Qv.x, Qv.y, Qv.z, Qv.w};
    Quat Bq{Bv.x, Bv.y, Bv.z, Bv.w};

    // Hillis-Steele inclusive scan of affine maps (earlier-first compose)
#pragma unroll
    for (int off = 1; off < 64; off <<= 1) {
        Quat Qo, Bo;
        Qo.r = __shfl_up(Q.r, off);  Qo.i = __shfl_up(Q.i, off);
        Qo.j = __shfl_up(Q.j, off);  Qo.k = __shfl_up(Q.k, off);
        Bo.r = __shfl_up(Bq.r, off); Bo.i = __shfl_up(Bq.i, off);
        Bo.j = __shfl_up(Bq.j, off); Bo.k = __shfl_up(Bq.k, off);
        if (lane >= off) {
            Bq = qmuladd(Q, Bo, Bq);   // B = Q_cur x B_prev + B_cur (uses old Q)
            Q  = qmul(Q, Qo);          // Q = Q_cur x Q_prev
        }
    }

    // h at chunk start = B-part of inclusive scan of previous lane (h0 = 0)
    float hr = __shfl_up(Bq.r, 1);
    float hi = __shfl_up(Bq.i, 1);
    float hj = __shfl_up(Bq.j, 1);
    float hk = __shfl_up(Bq.k, 1);
    if (lane == 0) { hr = 0.f; hi = 0.f; hj = 0.f; hk = 0.f; }
    *(float4*)(Wp + 4) = make_float4(hr, hi, hj, hk);
}

// ---------------- pass 3: replay with correct h_start, emit output -----------
// grid: (DQ/256, NCH, BSZ), block 256; each thread owns all 4 s channels.
__global__ __launch_bounds__(256) void qssm_pass3(
    const float* __restrict__ u, const float* __restrict__ dt,
    const float* __restrict__ Bin, const float* __restrict__ Cin,
    const float* __restrict__ Alog, const float* __restrict__ Ai,
    const float* __restrict__ Aj,   const float* __restrict__ Ak,
    const float* __restrict__ W, float* __restrict__ out)
{
    const int d = blockIdx.x * 256 + threadIdx.x;
    const int c = blockIdx.y;
    const int b = blockIdx.z;

    float4 hA[SQ];
    Quat   h[SQ];
#pragma unroll
    for (int s = 0; s < SQ; ++s) {
        hA[s] = load_hA(Alog, Ai, Aj, Ak, d * SQ + s);
        const float* Wp = W + ((((size_t)b * SQ + s) * NCH + c) * DQ + d) * 8;
        const float4 hv = *(const float4*)(Wp + 4);
        h[s] = Quat{hv.x, hv.y, hv.z, hv.w};
    }

    const int t0 = c * CHUNK;
    const float*  dtp  = dt + ((size_t)b * LSEQ + t0) * DQ + d;
    const float4* up   = (const float4*)u   + ((size_t)b * LSEQ + t0) * DQ + d;
    const float4* Bp   = (const float4*)Bin + ((size_t)b * LSEQ + t0) * SQ;
    const float4* Cp   = (const float4*)Cin + ((size_t)b * LSEQ + t0) * SQ;
    float4*       outp = (float4*)out + ((size_t)b * LSEQ + t0) * DQ + d;

#pragma unroll 2
    for (int j = 0; j < CHUNK; ++j) {
        const float  a  = dtp[j * DQ];
        const float4 uq = up[j * DQ];
        Quat y{0.f, 0.f, 0.f, 0.f};
#pragma unroll
        for (int s = 0; s < SQ; ++s) {
            const float4 Bq = Bp[j * SQ + s];   // block-uniform
            const float4 Cq = Cp[j * SQ + s];   // block-uniform
            Quat q, Bu;
            cayley_step(a, hA[s], Bq, uq, q, Bu);
            h[s] = qmuladd(q, h[s], Bu);
            y = qmuladd(Quat{Cq.x, Cq.y, Cq.z, Cq.w}, h[s], y);
        }
        outp[j * DQ] = make_float4(y.r, y.i, y.j, y.k);
    }
}

extern "C" void kernel_launch(void* const* d_in, const int* in_sizes, int n_in,
                              void* d_out, int out_size, void* d_ws, size_t ws_size,
                              hipStream_t stream) {
    const float* u    = (const float*)d_in[0];
    const float* dt   = (const float*)d_in[1];
    const float* Bin  = (const float*)d_in[2];
    const float* Cin  = (const float*)d_in[3];
    const float* Alog = (const float*)d_in[4];
    const float* Ai   = (const float*)d_in[5];
    const float* Aj   = (const float*)d_in[6];
    const float* Ak   = (const float*)d_in[7];
    float* out = (float*)d_out;
    float* W   = (float*)d_ws;   // needs BSZ*SQ*NCH*DQ*8*4 = 8 MiB

    dim3 g1(DQ / 256, SQ * NCH, BSZ);
    qssm_pass1<<<g1, 256, 0, stream>>>(u, dt, Bin, Alog, Ai, Aj, Ak, W);

    qssm_pass2<<<(BSZ * DQ * SQ) / 4, 256, 0, stream>>>(W);

    dim3 g3(DQ / 256, NCH, BSZ);
    qssm_pass3<<<g3, 256, 0, stream>>>(u, dt, Bin, Cin, Alog, Ai, Aj, Ak, W, out);
}